// Round 8
// baseline (73.589 us; speedup 1.0000x reference)
//
#include <hip/hip_runtime.h>
#include <hip/hip_fp16.h>

// SSIM loss: predict/gt (32,1,512,512) f32, 11-tap separable gaussian (sigma=1.5),
// VALID padding -> 502x502 per image, loss = 1 - mean(ssim_map).
//
// Round 8: two-kernel split with ROW-INTERLEAVED fp16 intermediate
// planes[img][orow][q=0..4][col] so K1's 5 channel-stores per thread land
// 1KB apart (one write stream per block, not five 16MB-apart streams).
// K1 on 16-row strips (2048 blocks -> 8 waves/SIMD).

constexpr int WIN = 11;
constexpr int H = 512, W = 512, NIMG = 32;
constexpr int OH = H - WIN + 1, OW = W - WIN + 1;  // 502
constexpr float C1 = 0.009801f;   // (0.01*9.9)^2
constexpr float C2 = 0.088209f;   // (0.03*9.9)^2
constexpr double TOTAL = (double)NIMG * (double)OH * (double)OW;

// K1 geometry: 16-row strips
constexpr int RPS1 = 16, NSTR1 = 32;
constexpr int NBLK1 = NIMG * NSTR1 * 2;          // 2048
// interleaved intermediate: [img][orow][q][col] halves
constexpr size_t ROWSTRIDE = 5 * (size_t)W;      // 2560 halves per (img,row)
constexpr size_t PLANES_TOTAL = (size_t)NIMG * OH * ROWSTRIDE + 64;  // +pad for window overreads
// K2 geometry: 4 cols/thread
constexpr int NG = 126;                          // ceil(504/4) col-groups
constexpr long long T2 = (long long)NIMG * OH * NG;   // 2,024,064
constexpr int NBLK2 = (int)((T2 + 255) / 256);   // 7907
constexpr size_t WS_BS_BYTES = 65536;            // blocksum region
constexpr size_t WS_NEEDED = WS_BS_BYTES + PLANES_TOTAL * sizeof(__half);

__device__ constexpr float WGT[WIN] = {
    0.0010285f, 0.0075988f, 0.0360008f, 0.1093607f, 0.2130054f,
    0.2660118f,
    0.2130054f, 0.1093607f, 0.0360008f, 0.0075988f, 0.0010285f};

__device__ __forceinline__ float h2f(unsigned short u) {
    __half_raw r; r.x = u;
    return __half2float(__half(r));
}

// ---------------- K1: vertical pass ----------------
template <int U>
__device__ __forceinline__ void vrow(int base, int r0,
                                     const float* __restrict__ p,
                                     const float* __restrict__ g,
                                     float (&hp)[WIN], float (&hg)[WIN],
                                     float (&hpp)[WIN], float (&hgg)[WIN],
                                     float (&hpg)[WIN],
                                     __half* __restrict__ op) {
    const int rin = base + U;
    const int rr = min(rin, H - 1);          // clamp (tail strip only)
    const float pv = p[(size_t)rr * W];
    const float gv = g[(size_t)rr * W];
    hp[U] = pv; hg[U] = gv;
    hpp[U] = pv * pv; hgg[U] = gv * gv; hpg[U] = pv * gv;

    const int ro = rin - (WIN - 1);
    if (ro >= r0 && ro < OH) {               // wave-uniform
        float a0 = 0.f, a1 = 0.f, a2 = 0.f, a3 = 0.f, a4 = 0.f;
#pragma unroll
        for (int k = 0; k < WIN; ++k) {
            const int s = (U + 1 + k) % WIN; // static after unroll
            const float w = WGT[k];
            a0 = fmaf(w, hp[s], a0);
            a1 = fmaf(w, hg[s], a1);
            a2 = fmaf(w, hpp[s], a2);
            a3 = fmaf(w, hgg[s], a3);
            a4 = fmaf(w, hpg[s], a4);
        }
        const size_t off = (size_t)ro * ROWSTRIDE;
        op[off + 0 * W] = __float2half(a0);
        op[off + 1 * W] = __float2half(a1);
        op[off + 2 * W] = __float2half(a2);
        op[off + 3 * W] = __float2half(a3);
        op[off + 4 * W] = __float2half(a4);
    }
}

__global__ __launch_bounds__(256) void vpass_kernel(const float* __restrict__ P,
                                                    const float* __restrict__ G,
                                                    __half* __restrict__ planes) {
    const int tid = threadIdx.x;
    const int bid = blockIdx.x;
    const int img = bid >> 6;          // 64 blocks/img (32 strips x 2 col-halves)
    const int sb = bid & 63;
    const int strip = sb >> 1;
    const int col = (sb & 1) * 256 + tid;   // 0..511, all valid

    const int r0 = strip * RPS1;

    const float* p = P + (size_t)img * H * W + col;
    const float* g = G + (size_t)img * H * W + col;
    __half* op = planes + (size_t)img * OH * ROWSTRIDE + col;

    float hp[WIN], hg[WIN], hpp[WIN], hgg[WIN], hpg[WIN];

    // 26 input rows: 2 x 11 + 4
    int base = r0;
#pragma unroll 1
    for (int ii = 0; ii < 2; ++ii, base += 11) {
        vrow<0>(base, r0, p, g, hp, hg, hpp, hgg, hpg, op);
        vrow<1>(base, r0, p, g, hp, hg, hpp, hgg, hpg, op);
        vrow<2>(base, r0, p, g, hp, hg, hpp, hgg, hpg, op);
        vrow<3>(base, r0, p, g, hp, hg, hpp, hgg, hpg, op);
        vrow<4>(base, r0, p, g, hp, hg, hpp, hgg, hpg, op);
        vrow<5>(base, r0, p, g, hp, hg, hpp, hgg, hpg, op);
        vrow<6>(base, r0, p, g, hp, hg, hpp, hgg, hpg, op);
        vrow<7>(base, r0, p, g, hp, hg, hpp, hgg, hpg, op);
        vrow<8>(base, r0, p, g, hp, hg, hpp, hgg, hpg, op);
        vrow<9>(base, r0, p, g, hp, hg, hpp, hgg, hpg, op);
        vrow<10>(base, r0, p, g, hp, hg, hpp, hgg, hpg, op);
    }
    vrow<0>(base, r0, p, g, hp, hg, hpp, hgg, hpg, op);
    vrow<1>(base, r0, p, g, hp, hg, hpp, hgg, hpg, op);
    vrow<2>(base, r0, p, g, hp, hg, hpp, hgg, hpg, op);
    vrow<3>(base, r0, p, g, hp, hg, hpp, hgg, hpg, op);
}

// ---------------- K2: horizontal pass + SSIM ----------------
__global__ __launch_bounds__(256) void hpass_kernel(const __half* __restrict__ planes,
                                                    float* __restrict__ blocksum) {
    const int tid = threadIdx.x;
    const long long t = (long long)blockIdx.x * 256 + tid;
    float lsum = 0.f;
    if (t < T2) {
        const int tt = (int)t;
        const int grp = tt % NG;
        const int rimg = tt / NG;          // img*502 + row
        const int c0 = grp * 4;
        const size_t base = (size_t)rimg * ROWSTRIDE + c0;

        float acc[4][5];
#pragma unroll
        for (int cc = 0; cc < 4; ++cc)
#pragma unroll
            for (int q = 0; q < 5; ++q) acc[cc][q] = 0.f;

#pragma unroll
        for (int q = 0; q < 5; ++q) {
            const __half* pl = planes + base + (size_t)q * W;
            float x[16];
#pragma unroll
            for (int i = 0; i < 4; ++i) {
                const short4 v = *(const short4*)(pl + 4 * i);
                x[4 * i + 0] = h2f((unsigned short)v.x);
                x[4 * i + 1] = h2f((unsigned short)v.y);
                x[4 * i + 2] = h2f((unsigned short)v.z);
                x[4 * i + 3] = h2f((unsigned short)v.w);
            }
#pragma unroll
            for (int cc = 0; cc < 4; ++cc) {
                float a = 0.f;
#pragma unroll
                for (int k = 0; k < WIN; ++k)
                    a = fmaf(WGT[k], x[cc + k], a);
                acc[cc][q] = a;
            }
        }

#pragma unroll
        for (int cc = 0; cc < 4; ++cc) {
            if (c0 + cc < OW) {
                const float m1 = acc[cc][0], m2 = acc[cc][1];
                const float e11 = acc[cc][2], e22 = acc[cc][3], e12 = acc[cc][4];
                const float mu11 = m1 * m1, mu22 = m2 * m2, mu12 = m1 * m2;
                const float s11 = e11 - mu11, s22 = e22 - mu22, s12 = e12 - mu12;
                const float num = (2.f * mu12 + C1) * (2.f * s12 + C2);
                const float den = (mu11 + mu22 + C1) * (s11 + s22 + C2);
                lsum += __fdividef(num, den);
            }
        }
    }

    // block reduction
#pragma unroll
    for (int off = 32; off > 0; off >>= 1)
        lsum += __shfl_down(lsum, off, 64);
    __shared__ float wsum[4];
    const int wid = tid >> 6, lane = tid & 63;
    if (lane == 0) wsum[wid] = lsum;
    __syncthreads();
    if (tid == 0)
        blocksum[blockIdx.x] = (wsum[0] + wsum[1]) + (wsum[2] + wsum[3]);
}

// ---------------- fallback single kernel (round-6, passed) ----------------
template <int U>
__device__ __forceinline__ void row_body(int base, int r0,
                                         const float* __restrict__ p,
                                         const float* __restrict__ g,
                                         float (&hp)[WIN], float (&hg)[WIN],
                                         float (&hpp)[WIN], float (&hgg)[WIN],
                                         float (&hpg)[WIN],
                                         bool active, float& lsum) {
    const int rin = base + U;
    const int rr = min(rin, H - 1);
    const float* rp = p + (size_t)rr * W;
    const float* rg = g + (size_t)rr * W;
    float a0 = 0.f, a1 = 0.f, a2 = 0.f, a3 = 0.f, a4 = 0.f;
#pragma unroll
    for (int k = 0; k < WIN; ++k) {
        const float pv = rp[k];
        const float gv = rg[k];
        const float w = WGT[k];
        const float wp = w * pv;
        a0 = fmaf(w, pv, a0);
        a1 = fmaf(w, gv, a1);
        a2 = fmaf(wp, pv, a2);
        a4 = fmaf(wp, gv, a4);
        a3 = fmaf(w * gv, gv, a3);
    }
    hp[U] = a0; hg[U] = a1; hpp[U] = a2; hgg[U] = a3; hpg[U] = a4;
    const int ro = rin - (WIN - 1);
    if (ro >= r0 && ro < OH) {
        float m1 = 0.f, m2 = 0.f, e11 = 0.f, e22 = 0.f, e12 = 0.f;
#pragma unroll
        for (int k = 0; k < WIN; ++k) {
            const int s = (U + 1 + k) % WIN;
            const float w = WGT[k];
            m1  = fmaf(w, hp[s], m1);
            m2  = fmaf(w, hg[s], m2);
            e11 = fmaf(w, hpp[s], e11);
            e22 = fmaf(w, hgg[s], e22);
            e12 = fmaf(w, hpg[s], e12);
        }
        const float mu11 = m1 * m1, mu22 = m2 * m2, mu12 = m1 * m2;
        const float s11 = e11 - mu11, s22 = e22 - mu22, s12 = e12 - mu12;
        const float num = (2.f * mu12 + C1) * (2.f * s12 + C2);
        const float den = (mu11 + mu22 + C1) * (s11 + s22 + C2);
        lsum += active ? __fdividef(num, den) : 0.f;
    }
}

__global__ __launch_bounds__(256) void ssim_stream_kernel(const float* __restrict__ P,
                                                          const float* __restrict__ G,
                                                          float* __restrict__ blocksum) {
    const int tid = threadIdx.x;
    const int bid = blockIdx.x;
    const int img = bid >> 5;
    const int sb = bid & 31;
    const int strip = sb >> 1;
    int col = (sb & 1) * 256 + tid;
    const bool active = col < OW;
    if (!active) col = OW - 1;
    const int r0 = strip * 32;
    const float* p = P + (size_t)img * H * W + col;
    const float* g = G + (size_t)img * H * W + col;
    float hp[WIN], hg[WIN], hpp[WIN], hgg[WIN], hpg[WIN];
    float lsum = 0.f;
    int base = r0;
#pragma unroll 1
    for (int ii = 0; ii < 3; ++ii, base += 11) {
        row_body<0>(base, r0, p, g, hp, hg, hpp, hgg, hpg, active, lsum);
        row_body<1>(base, r0, p, g, hp, hg, hpp, hgg, hpg, active, lsum);
        row_body<2>(base, r0, p, g, hp, hg, hpp, hgg, hpg, active, lsum);
        row_body<3>(base, r0, p, g, hp, hg, hpp, hgg, hpg, active, lsum);
        row_body<4>(base, r0, p, g, hp, hg, hpp, hgg, hpg, active, lsum);
        row_body<5>(base, r0, p, g, hp, hg, hpp, hgg, hpg, active, lsum);
        row_body<6>(base, r0, p, g, hp, hg, hpp, hgg, hpg, active, lsum);
        row_body<7>(base, r0, p, g, hp, hg, hpp, hgg, hpg, active, lsum);
        row_body<8>(base, r0, p, g, hp, hg, hpp, hgg, hpg, active, lsum);
        row_body<9>(base, r0, p, g, hp, hg, hpp, hgg, hpg, active, lsum);
        row_body<10>(base, r0, p, g, hp, hg, hpp, hgg, hpg, active, lsum);
    }
    row_body<0>(base, r0, p, g, hp, hg, hpp, hgg, hpg, active, lsum);
    row_body<1>(base, r0, p, g, hp, hg, hpp, hgg, hpg, active, lsum);
    row_body<2>(base, r0, p, g, hp, hg, hpp, hgg, hpg, active, lsum);
    row_body<3>(base, r0, p, g, hp, hg, hpp, hgg, hpg, active, lsum);
    row_body<4>(base, r0, p, g, hp, hg, hpp, hgg, hpg, active, lsum);
    row_body<5>(base, r0, p, g, hp, hg, hpp, hgg, hpg, active, lsum);
    row_body<6>(base, r0, p, g, hp, hg, hpp, hgg, hpg, active, lsum);
    row_body<7>(base, r0, p, g, hp, hg, hpp, hgg, hpg, active, lsum);
    row_body<8>(base, r0, p, g, hp, hg, hpp, hgg, hpg, active, lsum);
#pragma unroll
    for (int off = 32; off > 0; off >>= 1)
        lsum += __shfl_down(lsum, off, 64);
    __shared__ float wsum[4];
    const int wid = tid >> 6, lane = tid & 63;
    if (lane == 0) wsum[wid] = lsum;
    __syncthreads();
    if (tid == 0)
        blocksum[bid] = (wsum[0] + wsum[1]) + (wsum[2] + wsum[3]);
}

// ---------------- final reduce ----------------
__global__ __launch_bounds__(256) void reduce_kernel(const float* __restrict__ blocksum,
                                                     float* __restrict__ out, int n) {
    const int tid = threadIdx.x;
    float s = 0.f;
    for (int i = tid; i < n; i += 256) s += blocksum[i];
#pragma unroll
    for (int off = 32; off > 0; off >>= 1)
        s += __shfl_down(s, off, 64);
    __shared__ float wsum[4];
    const int wid = tid >> 6, lane = tid & 63;
    if (lane == 0) wsum[wid] = s;
    __syncthreads();
    if (tid == 0) {
        const float total = (wsum[0] + wsum[1]) + (wsum[2] + wsum[3]);
        out[0] = 1.f - total * (float)(1.0 / TOTAL);
    }
}

extern "C" void kernel_launch(void* const* d_in, const int* in_sizes, int n_in,
                              void* d_out, int out_size, void* d_ws, size_t ws_size,
                              hipStream_t stream) {
    const float* P = (const float*)d_in[0];
    const float* G = (const float*)d_in[1];
    float* out = (float*)d_out;
    float* blocksum = (float*)d_ws;

    if (ws_size >= WS_NEEDED) {
        __half* planes = (__half*)((char*)d_ws + WS_BS_BYTES);
        vpass_kernel<<<NBLK1, 256, 0, stream>>>(P, G, planes);
        hpass_kernel<<<NBLK2, 256, 0, stream>>>(planes, blocksum);
        reduce_kernel<<<1, 256, 0, stream>>>(blocksum, out, NBLK2);
    } else {
        ssim_stream_kernel<<<1024, 256, 0, stream>>>(P, G, blocksum);
        reduce_kernel<<<1, 256, 0, stream>>>(blocksum, out, 1024);
    }
}

// Round 9
// 59.869 us; speedup vs baseline: 1.2292x; 1.2292x over previous
//
#include <hip/hip_runtime.h>

// SSIM loss: predict/gt (32,1,512,512) f32, 11-tap separable gaussian (sigma=1.5),
// VALID padding -> 502x502 per image, loss = 1 - mean(ssim_map).
//
// Round 9: fused hybrid. Vertical conv per-thread in a 14-row register window
// (1 col/thread, 2 coalesced loads/row, static indices, shift-by-4 per chunk).
// 5 blurred channels bounce via LDS [4][5][272]; horizontal conv reads them as
// aligned b128 (4 cols/thread). 4-row chunks; next chunk's loads issued before
// the barrier so HBM latency hides under the horizontal FMA phase.

constexpr int WIN = 11;
constexpr int H = 512, W = 512, NIMG = 32;
constexpr int OH = H - WIN + 1, OW = W - WIN + 1;  // 502
constexpr int RPS = 32;                  // output rows per strip
constexpr int NSTRIP = 16;               // 16*32 = 512 >= 502
constexpr int BCOLS = 192;               // output cols per block
constexpr int NCB = 3;                   // 3*192 = 576 >= 502
constexpr int NBLK = NIMG * NSTRIP * NCB;  // 1536
constexpr int LW = 272;                  // LDS row width (reads reach c0+15 <= 267)
constexpr float C1 = 0.009801f;   // (0.01*9.9)^2
constexpr float C2 = 0.088209f;   // (0.03*9.9)^2
constexpr double TOTAL = (double)NIMG * (double)OH * (double)OW;

__device__ constexpr float WGT[WIN] = {
    0.0010285f, 0.0075988f, 0.0360008f, 0.1093607f, 0.2130054f,
    0.2660118f,
    0.2130054f, 0.1093607f, 0.0360008f, 0.0075988f, 0.0010285f};

__global__ __launch_bounds__(256) void ssim_hybrid_kernel(const float* __restrict__ P,
                                                          const float* __restrict__ G,
                                                          float* __restrict__ blocksum) {
    __shared__ float V[4][5][LW];

    const int tid = threadIdx.x;
    const int bid = blockIdx.x;
    const int img = bid / (NSTRIP * NCB);
    const int rem = bid % (NSTRIP * NCB);
    const int strip = rem / NCB;
    const int colblk = rem % NCB;

    const int r0 = strip * RPS;
    const int cin0 = colblk * BCOLS;
    const int col = min(cin0 + tid, W - 1);   // clamped; redundant lanes masked later

    const float* p = P + (size_t)img * H * W + col;
    const float* g = G + (size_t)img * H * W + col;

    // 14-row channel window: h[q][j] = channel q of input row (r0 + 4c + j)
    float h[5][14];

    // ---- warmup: rows r0..r0+9 (always <= 489+9 < 512, no clamp needed)
#pragma unroll
    for (int j = 0; j < 10; ++j) {
        const float pv = p[(size_t)(r0 + j) * W];
        const float gv = g[(size_t)(r0 + j) * W];
        h[0][j] = pv; h[1][j] = gv;
        h[2][j] = pv * pv; h[3][j] = gv * gv; h[4][j] = pv * gv;
    }
    // prefetch rows r0+10..r0+13
    float np[4], ng[4];
#pragma unroll
    for (int i = 0; i < 4; ++i) {
        const int rn = min(r0 + 10 + i, H - 1);
        np[i] = p[(size_t)rn * W];
        ng[i] = g[(size_t)rn * W];
    }

    const int hrow = tid >> 6;          // 0..3  (horizontal phase row)
    const int c0 = (tid & 63) * 4;      // 0..252 (horizontal phase col base)
    float lsum = 0.f;

#pragma unroll 1
    for (int c = 0; c < 8; ++c) {
        // consume prefetched rows -> window slots 10..13
#pragma unroll
        for (int i = 0; i < 4; ++i) {
            const float pv = np[i], gv = ng[i];
            h[0][10 + i] = pv; h[1][10 + i] = gv;
            h[2][10 + i] = pv * pv; h[3][10 + i] = gv * gv; h[4][10 + i] = pv * gv;
        }
        // issue next chunk's loads (rows r0+4c+14..17, clamped; wasted on c==7)
#pragma unroll
        for (int i = 0; i < 4; ++i) {
            const int rn = min(r0 + 4 * c + 14 + i, H - 1);
            np[i] = p[(size_t)rn * W];
            ng[i] = g[(size_t)rn * W];
        }
        // vertical conv: output rows r0+4c+rr, rr=0..3 -> LDS
#pragma unroll
        for (int rr = 0; rr < 4; ++rr) {
            float a0 = 0.f, a1 = 0.f, a2 = 0.f, a3 = 0.f, a4 = 0.f;
#pragma unroll
            for (int k = 0; k < WIN; ++k) {
                const float w = WGT[k];
                a0 = fmaf(w, h[0][rr + k], a0);
                a1 = fmaf(w, h[1][rr + k], a1);
                a2 = fmaf(w, h[2][rr + k], a2);
                a3 = fmaf(w, h[3][rr + k], a3);
                a4 = fmaf(w, h[4][rr + k], a4);
            }
            V[rr][0][tid] = a0; V[rr][1][tid] = a1; V[rr][2][tid] = a2;
            V[rr][3][tid] = a3; V[rr][4][tid] = a4;
        }
        __syncthreads();

        // horizontal conv + SSIM: thread -> (hrow, cols c0..c0+3)
        {
            float acc[4][5];
#pragma unroll
            for (int q = 0; q < 5; ++q) {
                float x[16];
#pragma unroll
                for (int i = 0; i < 4; ++i) {
                    const float4 v4 = *(const float4*)(&V[hrow][q][c0 + 4 * i]);
                    x[4 * i + 0] = v4.x; x[4 * i + 1] = v4.y;
                    x[4 * i + 2] = v4.z; x[4 * i + 3] = v4.w;
                }
#pragma unroll
                for (int cc = 0; cc < 4; ++cc) {
                    float a = 0.f;
#pragma unroll
                    for (int k = 0; k < WIN; ++k)
                        a = fmaf(WGT[k], x[cc + k], a);
                    acc[cc][q] = a;
                }
            }
            const int orow = r0 + 4 * c + hrow;
            const bool rowok = orow < OH;
#pragma unroll
            for (int cc = 0; cc < 4; ++cc) {
                const bool ok = rowok && ((c0 + cc) < BCOLS) && ((cin0 + c0 + cc) < OW);
                const float m1 = acc[cc][0], m2 = acc[cc][1];
                const float e11 = acc[cc][2], e22 = acc[cc][3], e12 = acc[cc][4];
                const float mu11 = m1 * m1, mu22 = m2 * m2, mu12 = m1 * m2;
                const float s11 = e11 - mu11, s22 = e22 - mu22, s12 = e12 - mu12;
                const float num = (2.f * mu12 + C1) * (2.f * s12 + C2);
                const float den = (mu11 + mu22 + C1) * (s11 + s22 + C2);
                const float ssim = __fdividef(num, den);
                lsum += ok ? ssim : 0.f;
            }
        }
        __syncthreads();

        // shift window by 4 rows
#pragma unroll
        for (int q = 0; q < 5; ++q)
#pragma unroll
            for (int j = 0; j < 10; ++j)
                h[q][j] = h[q][j + 4];
    }

    // block reduction
#pragma unroll
    for (int off = 32; off > 0; off >>= 1)
        lsum += __shfl_down(lsum, off, 64);
    __shared__ float wsum[4];
    const int wid = tid >> 6, lane = tid & 63;
    if (lane == 0) wsum[wid] = lsum;
    __syncthreads();
    if (tid == 0)
        blocksum[bid] = (wsum[0] + wsum[1]) + (wsum[2] + wsum[3]);
}

// one-block reduction of block sums -> loss scalar
__global__ __launch_bounds__(256) void reduce_kernel(const float* __restrict__ blocksum,
                                                     float* __restrict__ out, int n) {
    const int tid = threadIdx.x;
    float s = 0.f;
    for (int i = tid; i < n; i += 256) s += blocksum[i];
#pragma unroll
    for (int off = 32; off > 0; off >>= 1)
        s += __shfl_down(s, off, 64);
    __shared__ float wsum[4];
    const int wid = tid >> 6, lane = tid & 63;
    if (lane == 0) wsum[wid] = s;
    __syncthreads();
    if (tid == 0) {
        const float total = (wsum[0] + wsum[1]) + (wsum[2] + wsum[3]);
        out[0] = 1.f - total * (float)(1.0 / TOTAL);
    }
}

extern "C" void kernel_launch(void* const* d_in, const int* in_sizes, int n_in,
                              void* d_out, int out_size, void* d_ws, size_t ws_size,
                              hipStream_t stream) {
    const float* P = (const float*)d_in[0];   // predict
    const float* G = (const float*)d_in[1];   // gt
    float* out = (float*)d_out;
    float* blocksum = (float*)d_ws;           // NBLK floats

    ssim_hybrid_kernel<<<NBLK, 256, 0, stream>>>(P, G, blocksum);
    reduce_kernel<<<1, 256, 0, stream>>>(blocksum, out, NBLK);
}